// Round 1
// baseline (1484.550 us; speedup 1.0000x reference)
//
#include <hip/hip_runtime.h>
#include <hip/hip_bf16.h>
#include <math.h>

// Problem dims (fixed)
#define BB 32
#define LL 2048
#define DD 512
#define DA 512
#define NL 512

// GEMM tiling
constexpr int BM = 128, BN = 128, BKT = 16, PADT = 4, LDT = BM + PADT; // LDT=132

// ---------------------------------------------------------------------------
// Shared fp32 GEMM mainloop: C[128x128] += A_tile @ B_tile^T
//   A: rows are M-dim, K-contiguous (lda = row stride)
//   B_KCONTIG=true : B rows are N-dim, K-contiguous (like A) -> transpose-store
//   B_KCONTIG=false: B is [K, N] with N contiguous (row stride ldb)
// smem must hold 2*BKT*LDT floats.
// ---------------------------------------------------------------------------
template <bool B_KCONTIG>
__device__ __forceinline__ void gemm_mainloop(
    const float* __restrict__ Ap,   // &A[m0 * lda]
    const float* __restrict__ Bp,   // B_KCONTIG ? &B[n0*ldb] : &B[0*ldb + n0]
    int K, int lda, int ldb,
    float acc[8][8], float* smem)
{
    float (*As)[LDT] = (float(*)[LDT])smem;
    float (*Bs)[LDT] = (float(*)[LDT])(smem + BKT * LDT);
    const int tid = threadIdx.x;
    const int tx = tid & 15, ty = tid >> 4;

    for (int k0 = 0; k0 < K; k0 += BKT) {
        // ---- stage A: 128 rows x 16 k  (512 float4, 2 per thread), transposed
        #pragma unroll
        for (int it = 0; it < 2; ++it) {
            const int idx = tid + it * 256;
            const int row = idx >> 2, kq = idx & 3;
            const float4 av = *(const float4*)(Ap + (size_t)row * lda + k0 + kq * 4);
            As[kq * 4 + 0][row] = av.x;
            As[kq * 4 + 1][row] = av.y;
            As[kq * 4 + 2][row] = av.z;
            As[kq * 4 + 3][row] = av.w;
        }
        // ---- stage B
        if constexpr (B_KCONTIG) {
            #pragma unroll
            for (int it = 0; it < 2; ++it) {
                const int idx = tid + it * 256;
                const int row = idx >> 2, kq = idx & 3;
                const float4 bv = *(const float4*)(Bp + (size_t)row * ldb + k0 + kq * 4);
                Bs[kq * 4 + 0][row] = bv.x;
                Bs[kq * 4 + 1][row] = bv.y;
                Bs[kq * 4 + 2][row] = bv.z;
                Bs[kq * 4 + 3][row] = bv.w;
            }
        } else {
            #pragma unroll
            for (int it = 0; it < 2; ++it) {
                const int idx = tid + it * 256;
                const int kr = idx >> 5, f4 = idx & 31;
                const float4 bv = *(const float4*)(Bp + (size_t)(k0 + kr) * ldb + f4 * 4);
                *(float4*)&Bs[kr][f4 * 4] = bv;
            }
        }
        __syncthreads();

        // ---- compute: 16 k-steps, 8x8 rank-1 per thread
        #pragma unroll
        for (int k = 0; k < BKT; ++k) {
            const float4 a0 = *(const float4*)&As[k][ty * 8];
            const float4 a1 = *(const float4*)&As[k][ty * 8 + 4];
            const float4 b0 = *(const float4*)&Bs[k][tx * 8];
            const float4 b1 = *(const float4*)&Bs[k][tx * 8 + 4];
            const float av[8] = {a0.x, a0.y, a0.z, a0.w, a1.x, a1.y, a1.z, a1.w};
            const float bv[8] = {b0.x, b0.y, b0.z, b0.w, b1.x, b1.y, b1.z, b1.w};
            #pragma unroll
            for (int i = 0; i < 8; ++i)
                #pragma unroll
                for (int j = 0; j < 8; ++j)
                    acc[i][j] = fmaf(av[i], bv[j], acc[i][j]);
        }
        __syncthreads();
    }
}

// ---------------------------------------------------------------------------
// K1: W[m, a] = tanh( sum_d X[m,d] * W1[a,d] )   M=B*L=65536, N=DA, K=D
// ---------------------------------------------------------------------------
__global__ __launch_bounds__(256, 2) void k_gemm1_tanh(
    const float* __restrict__ X, const float* __restrict__ W1,
    float* __restrict__ Wout)
{
    __shared__ float smem[2 * BKT * LDT];
    const int n0 = blockIdx.x * BN;
    const int m0 = blockIdx.y * BM;
    float acc[8][8] = {};
    gemm_mainloop<true>(X + (size_t)m0 * DD, W1 + (size_t)n0 * DD, DD, DD, DD, acc, smem);

    const int tx = threadIdx.x & 15, ty = threadIdx.x >> 4;
    float* op = Wout + (size_t)(m0 + ty * 8) * DA + n0 + tx * 8;
    #pragma unroll
    for (int i = 0; i < 8; ++i) {
        float4 v0, v1;
        v0.x = tanhf(acc[i][0]); v0.y = tanhf(acc[i][1]);
        v0.z = tanhf(acc[i][2]); v0.w = tanhf(acc[i][3]);
        v1.x = tanhf(acc[i][4]); v1.y = tanhf(acc[i][5]);
        v1.z = tanhf(acc[i][6]); v1.w = tanhf(acc[i][7]);
        *(float4*)(op + (size_t)i * DA)     = v0;
        *(float4*)(op + (size_t)i * DA + 4) = v1;
    }
}

// ---------------------------------------------------------------------------
// K2: att[b, n, l] = sum_a W2[n,a] * W[b*L+l, a]   (transposed logits, direct)
// rows (M) = NL, cols (N) = B*L global l index
// ---------------------------------------------------------------------------
__global__ __launch_bounds__(256, 2) void k_gemm2_logitsT(
    const float* __restrict__ Wws, const float* __restrict__ W2,
    float* __restrict__ att)
{
    __shared__ float smem[2 * BKT * LDT];
    const int c0 = blockIdx.x * BN;   // global l tile (within one batch: 2048%128==0)
    const int m0 = blockIdx.y * BM;   // over NL
    float acc[8][8] = {};
    gemm_mainloop<true>(W2 + (size_t)m0 * DA, Wws + (size_t)c0 * DA, DA, DA, DA, acc, smem);

    const int b = c0 >> 11, lloc = c0 & (LL - 1);
    const int tx = threadIdx.x & 15, ty = threadIdx.x >> 4;
    float* op = att + ((size_t)b * NL + m0 + ty * 8) * LL + lloc + tx * 8;
    #pragma unroll
    for (int i = 0; i < 8; ++i) {
        float4 v0, v1;
        v0.x = acc[i][0]; v0.y = acc[i][1]; v0.z = acc[i][2]; v0.w = acc[i][3];
        v1.x = acc[i][4]; v1.y = acc[i][5]; v1.z = acc[i][6]; v1.w = acc[i][7];
        *(float4*)(op + (size_t)i * LL)     = v0;
        *(float4*)(op + (size_t)i * LL + 4) = v1;
    }
}

// ---------------------------------------------------------------------------
// K3: softmax over contiguous L for each (b, n) row, in place
// ---------------------------------------------------------------------------
__global__ __launch_bounds__(256) void k_softmax(float* __restrict__ att)
{
    const int tid = threadIdx.x;
    float* p = att + (size_t)blockIdx.x * LL;
    float4 v0 = *(const float4*)&p[tid * 4];
    float4 v1 = *(const float4*)&p[1024 + tid * 4];

    __shared__ float red[8];
    float m = fmaxf(fmaxf(fmaxf(v0.x, v0.y), fmaxf(v0.z, v0.w)),
                    fmaxf(fmaxf(v1.x, v1.y), fmaxf(v1.z, v1.w)));
    #pragma unroll
    for (int off = 32; off; off >>= 1) m = fmaxf(m, __shfl_down(m, off));
    if ((tid & 63) == 0) red[tid >> 6] = m;
    __syncthreads();
    m = fmaxf(fmaxf(red[0], red[1]), fmaxf(red[2], red[3]));

    v0.x = __expf(v0.x - m); v0.y = __expf(v0.y - m);
    v0.z = __expf(v0.z - m); v0.w = __expf(v0.w - m);
    v1.x = __expf(v1.x - m); v1.y = __expf(v1.y - m);
    v1.z = __expf(v1.z - m); v1.w = __expf(v1.w - m);
    float s = v0.x + v0.y + v0.z + v0.w + v1.x + v1.y + v1.z + v1.w;
    #pragma unroll
    for (int off = 32; off; off >>= 1) s += __shfl_down(s, off);
    if ((tid & 63) == 0) red[4 + (tid >> 6)] = s;
    __syncthreads();
    s = red[4] + red[5] + red[6] + red[7];

    const float inv = 1.0f / s;
    v0.x *= inv; v0.y *= inv; v0.z *= inv; v0.w *= inv;
    v1.x *= inv; v1.y *= inv; v1.z *= inv; v1.w *= inv;
    *(float4*)&p[tid * 4] = v0;
    *(float4*)&p[1024 + tid * 4] = v1;
}

// ---------------------------------------------------------------------------
// K4: ctx[b, n, d] = sum_l att[b,n,l] * x[b,l,d]
// ---------------------------------------------------------------------------
__global__ __launch_bounds__(256, 2) void k_gemm3_ctx(
    const float* __restrict__ att, const float* __restrict__ x,
    float* __restrict__ ctx)
{
    __shared__ float smem[2 * BKT * LDT];
    const int b = blockIdx.z;
    const int n0 = blockIdx.x * BN;   // over D
    const int m0 = blockIdx.y * BM;   // over NL
    const float* Ab = att + (size_t)b * NL * LL;
    const float* Xb = x + (size_t)b * LL * DD;
    float acc[8][8] = {};
    gemm_mainloop<false>(Ab + (size_t)m0 * LL, Xb + n0, LL, LL, DD, acc, smem);

    const int tx = threadIdx.x & 15, ty = threadIdx.x >> 4;
    float* op = ctx + ((size_t)b * NL + m0 + ty * 8) * DD + n0 + tx * 8;
    #pragma unroll
    for (int i = 0; i < 8; ++i) {
        float4 v0, v1;
        v0.x = acc[i][0]; v0.y = acc[i][1]; v0.z = acc[i][2]; v0.w = acc[i][3];
        v1.x = acc[i][4]; v1.y = acc[i][5]; v1.z = acc[i][6]; v1.w = acc[i][7];
        *(float4*)(op + (size_t)i * DD)     = v0;
        *(float4*)(op + (size_t)i * DD + 4) = v1;
    }
}

// ---------------------------------------------------------------------------
// K5: wo[b, n] = sum_d ctx[b,n,d] * W3[n,d] + b3[n]   (one wave per (b,n))
// ---------------------------------------------------------------------------
__global__ __launch_bounds__(256) void k_wo(
    const float* __restrict__ ctx, const float* __restrict__ W3,
    const float* __restrict__ b3, float* __restrict__ wo)
{
    const int gw = blockIdx.x * 4 + (threadIdx.x >> 6);
    const int lane = threadIdx.x & 63;
    const int n = gw & (NL - 1);
    const float* c = ctx + (size_t)gw * DD;
    const float* w = W3 + (size_t)n * DD;
    float s = 0.f;
    #pragma unroll
    for (int it = 0; it < 2; ++it) {
        const float4 a = *(const float4*)&c[(it * 64 + lane) * 4];
        const float4 b = *(const float4*)&w[(it * 64 + lane) * 4];
        s += a.x * b.x + a.y * b.y + a.z * b.z + a.w * b.w;
    }
    #pragma unroll
    for (int off = 32; off; off >>= 1) s += __shfl_down(s, off);
    if (lane == 0) wo[gw] = s + b3[n];
}

// ---------------------------------------------------------------------------
extern "C" void kernel_launch(void* const* d_in, const int* in_sizes, int n_in,
                              void* d_out, int out_size, void* d_ws, size_t ws_size,
                              hipStream_t stream)
{
    const float* x  = (const float*)d_in[0];
    const float* W1 = (const float*)d_in[1];
    const float* W2 = (const float*)d_in[2];
    const float* W3 = (const float*)d_in[3];
    const float* b3 = (const float*)d_in[4];

    float* out = (float*)d_out;
    float* ctx = out;                               // [B, NL, D]
    float* wo  = out + (size_t)BB * NL * DD;        // [B, NL]
    float* att = wo + (size_t)BB * NL;              // [B, NL, L]
    float* Wws = (float*)d_ws;                      // [B*L, DA] fp32 (134 MB)

    // 1) w = tanh(x @ W1^T)
    k_gemm1_tanh<<<dim3(DA / BN, (BB * LL) / BM), 256, 0, stream>>>(x, W1, Wws);
    // 2) logits^T -> att[b, n, l]
    k_gemm2_logitsT<<<dim3((BB * LL) / BN, NL / BM), 256, 0, stream>>>(Wws, W2, att);
    // 3) softmax over l (contiguous rows), in place
    k_softmax<<<dim3(BB * NL), 256, 0, stream>>>(att);
    // 4) ctx = att @ x  (per batch)
    k_gemm3_ctx<<<dim3(DD / BN, NL / BM, BB), 256, 0, stream>>>(att, x, ctx);
    // 5) wo = rowdot(ctx, W3) + b3
    k_wo<<<dim3((BB * NL) / 4), 256, 0, stream>>>(ctx, W3, b3, wo);
}

// Round 2
// 562.316 us; speedup vs baseline: 2.6401x; 2.6401x over previous
//
#include <hip/hip_runtime.h>
#include <math.h>

// Problem dims (fixed)
#define BB 32
#define LL 2048
#define DD 512
#define DA_ 512
#define NL_ 512

typedef __bf16 bf16;
typedef __bf16 bf16x8 __attribute__((ext_vector_type(8)));
typedef __bf16 bf16x4 __attribute__((ext_vector_type(4)));
typedef float floatx4 __attribute__((ext_vector_type(4)));

// async global->LDS, 16B per lane; LDS dest must be wave-uniform-base + lane*16
__device__ __forceinline__ void dma16(const void* g, void* l) {
    __builtin_amdgcn_global_load_lds((__attribute__((address_space(1))) void*)g,
                                     (__attribute__((address_space(3))) void*)l,
                                     16, 0, 0);
}

__device__ __forceinline__ float fast_tanh(float x) {
    // tanh(x) = 1 - 2/(exp(2x)+1); graceful at +-inf. ~1e-6 rel err, << bf16 ulp.
    const float e = __expf(2.f * x);
    return 1.f - 2.f * __builtin_amdgcn_rcpf(e + 1.f);
}

// ---------------------------------------------------------------------------
// bf16 MFMA GEMM core: C[128x128] += A[128xK] * B[128xK]^T, BK=32.
// A rows = M-dim, B rows = N-dim, both K-contiguous.
// AF/BF: operand is fp32 in global -> convert during LDS staging.
//        else bf16 in global -> global_load_lds dma.
// 256 threads = 4 waves; wave (wr,wc) owns a 64x64 quadrant, 4x4 16x16 tiles.
// ---------------------------------------------------------------------------
template <bool AF, bool BF>
__device__ __forceinline__ void gemm_core(const void* Ap_, const void* Bp_,
                                          int K, int lda, int ldb,
                                          floatx4 acc[4][4])
{
    __shared__ bf16 As[128 * 32];   // [row][32 k] row-major, 8 KB
    __shared__ bf16 Bs[128 * 32];
    const int tid = threadIdx.x;
    const int lane = tid & 63, wv = tid >> 6;
    const int wr = wv >> 1, wc = wv & 1;
    const int lm = lane & 15, quad = lane >> 4;

    for (int k0 = 0; k0 < K; k0 += 32) {
        __syncthreads();   // prior-iter fragment reads done before overwrite
        if constexpr (AF) {
            const float* A = (const float*)Ap_;
            #pragma unroll
            for (int it = 0; it < 4; ++it) {
                const int c = tid + it * 256;          // 1024 chunks of 4 floats
                const int row = c >> 3, kq = c & 7;
                const float4 v = *(const float4*)(A + (size_t)row * lda + k0 + kq * 4);
                bf16x4 p = {(bf16)v.x, (bf16)v.y, (bf16)v.z, (bf16)v.w};
                *(bf16x4*)(As + row * 32 + kq * 4) = p;
            }
        } else {
            const bf16* A = (const bf16*)Ap_;
            #pragma unroll
            for (int it = 0; it < 2; ++it) {
                const int c = tid + it * 256;          // 512 chunks of 16 B
                const int row = c >> 2, kq = c & 3;
                dma16(A + (size_t)row * lda + k0 + kq * 8, As + c * 8);
            }
        }
        if constexpr (BF) {
            const float* Bq = (const float*)Bp_;
            #pragma unroll
            for (int it = 0; it < 4; ++it) {
                const int c = tid + it * 256;
                const int row = c >> 3, kq = c & 7;
                const float4 v = *(const float4*)(Bq + (size_t)row * ldb + k0 + kq * 4);
                bf16x4 p = {(bf16)v.x, (bf16)v.y, (bf16)v.z, (bf16)v.w};
                *(bf16x4*)(Bs + row * 32 + kq * 4) = p;
            }
        } else {
            const bf16* Bq = (const bf16*)Bp_;
            #pragma unroll
            for (int it = 0; it < 2; ++it) {
                const int c = tid + it * 256;
                const int row = c >> 2, kq = c & 3;
                dma16(Bq + (size_t)row * ldb + k0 + kq * 8, Bs + c * 8);
            }
        }
        __syncthreads();

        bf16x8 af[4], bfr[4];
        #pragma unroll
        for (int t = 0; t < 4; ++t) {
            af[t]  = *(const bf16x8*)(As + (wr * 64 + t * 16 + lm) * 32 + quad * 8);
            bfr[t] = *(const bf16x8*)(Bs + (wc * 64 + t * 16 + lm) * 32 + quad * 8);
        }
        #pragma unroll
        for (int i = 0; i < 4; ++i)
            #pragma unroll
            for (int j = 0; j < 4; ++j)
                acc[i][j] = __builtin_amdgcn_mfma_f32_16x16x32_bf16(af[i], bfr[j], acc[i][j], 0, 0, 0);
    }
}

// C/D layout (verified m89): col = lane&15, row = quad*4 + reg.

// ---------------------------------------------------------------------------
// K0: xT[b, d, l] = bf16(x[b, l, d])  -- 64x64 tiles via LDS
// ---------------------------------------------------------------------------
__global__ __launch_bounds__(256) void k_transpose(const float* __restrict__ x,
                                                   bf16* __restrict__ xT)
{
    __shared__ float T[64][68];
    const int b = blockIdx.z;
    const int l0 = blockIdx.x * 64, d0 = blockIdx.y * 64;
    const int tid = threadIdx.x;
    const float* xb = x + ((size_t)b * LL + l0) * DD + d0;
    #pragma unroll
    for (int it = 0; it < 4; ++it) {
        const int c = tid + it * 256;
        const int lr = c >> 4, cc = (c & 15) * 4;
        const float4 v = *(const float4*)(xb + (size_t)lr * DD + cc);
        T[lr][cc] = v.x; T[lr][cc + 1] = v.y; T[lr][cc + 2] = v.z; T[lr][cc + 3] = v.w;
    }
    __syncthreads();
    const int dl = tid >> 2, ls = (tid & 3) * 16;
    bf16x8 p0, p1;
    #pragma unroll
    for (int j = 0; j < 8; ++j) p0[j] = (bf16)T[ls + j][dl];
    #pragma unroll
    for (int j = 0; j < 8; ++j) p1[j] = (bf16)T[ls + 8 + j][dl];
    bf16* o = xT + ((size_t)b * DD + d0 + dl) * LL + l0 + ls;
    *(bf16x8*)o = p0;
    *(bf16x8*)(o + 8) = p1;
}

// ---------------------------------------------------------------------------
// K1: wb[m, a] = bf16(tanh(sum_d x[m,d] * W1[a,d]))   M=B*L, N=DA, K=D
// ---------------------------------------------------------------------------
__global__ __launch_bounds__(256) void k_gemm1(const float* __restrict__ x,
                                               const float* __restrict__ W1,
                                               bf16* __restrict__ wb)
{
    const int n0 = blockIdx.x * 128;
    const size_t m0 = (size_t)blockIdx.y * 128;
    floatx4 acc[4][4];
    #pragma unroll
    for (int i = 0; i < 4; ++i)
        #pragma unroll
        for (int j = 0; j < 4; ++j) { floatx4 z = {0.f, 0.f, 0.f, 0.f}; acc[i][j] = z; }
    gemm_core<true, true>(x + m0 * DD, W1 + (size_t)n0 * DD, DD, DD, DD, acc);

    const int tid = threadIdx.x, lane = tid & 63, wv = tid >> 6;
    const int wr = wv >> 1, wc = wv & 1, lm = lane & 15, quad = lane >> 4;
    const size_t row0 = m0 + wr * 64 + quad * 4;
    const int col0 = n0 + wc * 64 + lm;
    #pragma unroll
    for (int i = 0; i < 4; ++i)
        #pragma unroll
        for (int j = 0; j < 4; ++j)
            #pragma unroll
            for (int r = 0; r < 4; ++r)
                wb[(row0 + i * 16 + r) * DA_ + col0 + j * 16] = (bf16)fast_tanh(acc[i][j][r]);
}

// ---------------------------------------------------------------------------
// K2: att[b, n, l] = sum_a W2[n,a] * wb[b*L+l, a]   (transposed logits direct)
// ---------------------------------------------------------------------------
__global__ __launch_bounds__(256) void k_gemm2(const bf16* __restrict__ wb,
                                               const float* __restrict__ W2,
                                               float* __restrict__ att)
{
    const int c0 = blockIdx.x * 128;   // global l index (128 never straddles a batch)
    const int m0 = blockIdx.y * 128;   // over NL
    floatx4 acc[4][4];
    #pragma unroll
    for (int i = 0; i < 4; ++i)
        #pragma unroll
        for (int j = 0; j < 4; ++j) { floatx4 z = {0.f, 0.f, 0.f, 0.f}; acc[i][j] = z; }
    gemm_core<true, false>(W2 + (size_t)m0 * DA_, wb + (size_t)c0 * DA_, DA_, DA_, DA_, acc);

    const int b = c0 >> 11, lloc = c0 & (LL - 1);
    const int tid = threadIdx.x, lane = tid & 63, wv = tid >> 6;
    const int wr = wv >> 1, wc = wv & 1, lm = lane & 15, quad = lane >> 4;
    float* base = att + ((size_t)b * NL_ + m0 + wr * 64 + quad * 4) * LL
                + lloc + wc * 64 + lm;
    #pragma unroll
    for (int i = 0; i < 4; ++i)
        #pragma unroll
        for (int j = 0; j < 4; ++j)
            #pragma unroll
            for (int r = 0; r < 4; ++r)
                base[(size_t)(i * 16 + r) * LL + j * 16] = acc[i][j][r];
}

// ---------------------------------------------------------------------------
// K3: softmax over contiguous L per (b,n); fp32 in-place + bf16 copy
// ---------------------------------------------------------------------------
__global__ __launch_bounds__(256) void k_softmax(float* __restrict__ att,
                                                 bf16* __restrict__ attb)
{
    const int tid = threadIdx.x;
    float* p = att + (size_t)blockIdx.x * LL;
    bf16* pb = attb + (size_t)blockIdx.x * LL;
    float4 v0 = *(const float4*)&p[tid * 4];
    float4 v1 = *(const float4*)&p[1024 + tid * 4];

    __shared__ float red[8];
    float m = fmaxf(fmaxf(fmaxf(v0.x, v0.y), fmaxf(v0.z, v0.w)),
                    fmaxf(fmaxf(v1.x, v1.y), fmaxf(v1.z, v1.w)));
    #pragma unroll
    for (int off = 32; off; off >>= 1) m = fmaxf(m, __shfl_down(m, off));
    if ((tid & 63) == 0) red[tid >> 6] = m;
    __syncthreads();
    m = fmaxf(fmaxf(red[0], red[1]), fmaxf(red[2], red[3]));

    v0.x = __expf(v0.x - m); v0.y = __expf(v0.y - m);
    v0.z = __expf(v0.z - m); v0.w = __expf(v0.w - m);
    v1.x = __expf(v1.x - m); v1.y = __expf(v1.y - m);
    v1.z = __expf(v1.z - m); v1.w = __expf(v1.w - m);
    float s = v0.x + v0.y + v0.z + v0.w + v1.x + v1.y + v1.z + v1.w;
    #pragma unroll
    for (int off = 32; off; off >>= 1) s += __shfl_down(s, off);
    if ((tid & 63) == 0) red[4 + (tid >> 6)] = s;
    __syncthreads();
    s = red[4] + red[5] + red[6] + red[7];

    const float inv = 1.0f / s;
    v0.x *= inv; v0.y *= inv; v0.z *= inv; v0.w *= inv;
    v1.x *= inv; v1.y *= inv; v1.z *= inv; v1.w *= inv;
    *(float4*)&p[tid * 4] = v0;
    *(float4*)&p[1024 + tid * 4] = v1;
    bf16x4 q0 = {(bf16)v0.x, (bf16)v0.y, (bf16)v0.z, (bf16)v0.w};
    bf16x4 q1 = {(bf16)v1.x, (bf16)v1.y, (bf16)v1.z, (bf16)v1.w};
    *(bf16x4*)(pb + tid * 4) = q0;
    *(bf16x4*)(pb + 1024 + tid * 4) = q1;
}

// ---------------------------------------------------------------------------
// K4: ctx[b, n, d] = sum_l attb[b,n,l] * xT[b,d,l]
// ---------------------------------------------------------------------------
__global__ __launch_bounds__(256) void k_gemm3(const bf16* __restrict__ attb,
                                               const bf16* __restrict__ xT,
                                               float* __restrict__ ctx)
{
    const int b = blockIdx.z;
    const int n0 = blockIdx.x * 128;   // over D
    const int m0 = blockIdx.y * 128;   // over NL
    floatx4 acc[4][4];
    #pragma unroll
    for (int i = 0; i < 4; ++i)
        #pragma unroll
        for (int j = 0; j < 4; ++j) { floatx4 z = {0.f, 0.f, 0.f, 0.f}; acc[i][j] = z; }
    gemm_core<false, false>(attb + ((size_t)b * NL_ + m0) * LL,
                            xT + ((size_t)b * DD + n0) * LL, LL, LL, LL, acc);

    const int tid = threadIdx.x, lane = tid & 63, wv = tid >> 6;
    const int wr = wv >> 1, wc = wv & 1, lm = lane & 15, quad = lane >> 4;
    float* base = ctx + ((size_t)b * NL_ + m0 + wr * 64 + quad * 4) * DD
                + n0 + wc * 64 + lm;
    #pragma unroll
    for (int i = 0; i < 4; ++i)
        #pragma unroll
        for (int j = 0; j < 4; ++j)
            #pragma unroll
            for (int r = 0; r < 4; ++r)
                base[(size_t)(i * 16 + r) * DD + j * 16] = acc[i][j][r];
}

// ---------------------------------------------------------------------------
// K5: wo[b, n] = sum_d ctx[b,n,d] * W3[n,d] + b3[n]   (one wave per (b,n))
// ---------------------------------------------------------------------------
__global__ __launch_bounds__(256) void k_wo(
    const float* __restrict__ ctx, const float* __restrict__ W3,
    const float* __restrict__ b3, float* __restrict__ wo)
{
    const int gw = blockIdx.x * 4 + (threadIdx.x >> 6);
    const int lane = threadIdx.x & 63;
    const int n = gw & (NL_ - 1);
    const float* c = ctx + (size_t)gw * DD;
    const float* w = W3 + (size_t)n * DD;
    float s = 0.f;
    #pragma unroll
    for (int it = 0; it < 2; ++it) {
        const float4 a = *(const float4*)&c[(it * 64 + lane) * 4];
        const float4 b = *(const float4*)&w[(it * 64 + lane) * 4];
        s += a.x * b.x + a.y * b.y + a.z * b.z + a.w * b.w;
    }
    #pragma unroll
    for (int off = 32; off; off >>= 1) s += __shfl_down(s, off);
    if (lane == 0) wo[gw] = s + b3[n];
}

// ---------------------------------------------------------------------------
extern "C" void kernel_launch(void* const* d_in, const int* in_sizes, int n_in,
                              void* d_out, int out_size, void* d_ws, size_t ws_size,
                              hipStream_t stream)
{
    const float* x  = (const float*)d_in[0];
    const float* W1 = (const float*)d_in[1];
    const float* W2 = (const float*)d_in[2];
    const float* W3 = (const float*)d_in[3];
    const float* b3 = (const float*)d_in[4];

    float* out = (float*)d_out;
    float* ctx = out;                               // [B, NL, D]
    float* wo  = out + (size_t)BB * NL_ * DD;       // [B, NL]
    float* att = wo + (size_t)BB * NL_;             // [B, NL, L]

    bf16* xT = (bf16*)d_ws;                                 // [B, D, L]  64 MiB
    bf16* wb = (bf16*)((char*)d_ws + (size_t)64 * 1024 * 1024); // [B*L, DA] 64 MiB
    bf16* attb = wb;                                        // overlay: wb dead after gemm2

    k_transpose<<<dim3(LL / 64, DD / 64, BB), 256, 0, stream>>>(x, xT);
    k_gemm1<<<dim3(DA_ / 128, (BB * LL) / 128), 256, 0, stream>>>(x, W1, wb);
    k_gemm2<<<dim3((BB * LL) / 128, NL_ / 128), 256, 0, stream>>>(wb, W2, att);
    k_softmax<<<BB * NL_, 256, 0, stream>>>(att, attb);
    k_gemm3<<<dim3(DD / 128, NL_ / 128, BB), 256, 0, stream>>>(attb, xT, ctx);
    k_wo<<<(BB * NL_) / 4, 256, 0, stream>>>(ctx, W3, b3, wo);
}

// Round 3
// 524.430 us; speedup vs baseline: 2.8308x; 1.0722x over previous
//
#include <hip/hip_runtime.h>
#include <math.h>

// Problem dims (fixed)
#define BB 32
#define LL 2048
#define DD 512
#define DA_ 512
#define NL_ 512

typedef __bf16 bf16;
typedef __bf16 bf16x8 __attribute__((ext_vector_type(8)));
typedef __bf16 bf16x4 __attribute__((ext_vector_type(4)));
typedef float floatx4 __attribute__((ext_vector_type(4)));

// async global->LDS, 16B per lane; LDS dest is wave-uniform base + lane*16
__device__ __forceinline__ void dma16(const void* g, void* l) {
    __builtin_amdgcn_global_load_lds((__attribute__((address_space(1))) void*)g,
                                     (__attribute__((address_space(3))) void*)l,
                                     16, 0, 0);
}

__device__ __forceinline__ float fast_tanh(float x) {
    const float e = __expf(2.f * x);
    return 1.f - 2.f * __builtin_amdgcn_rcpf(e + 1.f);
}

// ---------------------------------------------------------------------------
// Pure-DMA bf16 MFMA GEMM core: C[128x128] += A[128xK] * B[128xK]^T, BK=32.
// A rows = M-dim, B rows = N-dim, both K-contiguous bf16 in global.
// 256 threads = 4 waves; wave (wr,wc) owns a 64x64 quadrant, 4x4 16x16 tiles.
// ---------------------------------------------------------------------------
__device__ __forceinline__ void gemm_core(const bf16* __restrict__ A,
                                          const bf16* __restrict__ B,
                                          int K, int lda, int ldb,
                                          floatx4 acc[4][4])
{
    __shared__ bf16 As[128 * 32];   // 8 KB each
    __shared__ bf16 Bs[128 * 32];
    const int tid = threadIdx.x;
    const int lane = tid & 63, wv = tid >> 6;
    const int wr = wv >> 1, wc = wv & 1;
    const int lm = lane & 15, quad = lane >> 4;

    for (int k0 = 0; k0 < K; k0 += 32) {
        __syncthreads();   // prior-iter fragment reads done before overwrite
        #pragma unroll
        for (int it = 0; it < 2; ++it) {
            const int c = tid + it * 256;          // 512 chunks of 16 B
            const int row = c >> 2, kq = c & 3;
            dma16(A + (size_t)row * lda + k0 + kq * 8, As + c * 8);
        }
        #pragma unroll
        for (int it = 0; it < 2; ++it) {
            const int c = tid + it * 256;
            const int row = c >> 2, kq = c & 3;
            dma16(B + (size_t)row * ldb + k0 + kq * 8, Bs + c * 8);
        }
        __syncthreads();   // compiler drains vmcnt before s_barrier

        bf16x8 af[4], bfr[4];
        #pragma unroll
        for (int t = 0; t < 4; ++t) {
            af[t]  = *(const bf16x8*)(As + (wr * 64 + t * 16 + lm) * 32 + quad * 8);
            bfr[t] = *(const bf16x8*)(Bs + (wc * 64 + t * 16 + lm) * 32 + quad * 8);
        }
        #pragma unroll
        for (int i = 0; i < 4; ++i)
            #pragma unroll
            for (int j = 0; j < 4; ++j)
                acc[i][j] = __builtin_amdgcn_mfma_f32_16x16x32_bf16(af[i], bfr[j], acc[i][j], 0, 0, 0);
    }
}
// C/D layout (verified m89): col = lane&15, row = quad*4 + reg.

// ---------------------------------------------------------------------------
// K_cvt: fp32 -> bf16, n elements (n % 1024 == 0)
// ---------------------------------------------------------------------------
__global__ __launch_bounds__(256) void k_cvt(const float* __restrict__ src,
                                             bf16* __restrict__ dst, int n)
{
    const int i = (blockIdx.x * 256 + threadIdx.x) * 4;
    if (i < n) {
        const float4 v = *(const float4*)(src + i);
        bf16x4 p = {(bf16)v.x, (bf16)v.y, (bf16)v.z, (bf16)v.w};
        *(bf16x4*)(dst + i) = p;
    }
}

// ---------------------------------------------------------------------------
// K0: xT[b, d, l] = bf16(x[b, l, d])  AND  xb[b, l, d] = bf16(x[b, l, d])
// 64x64 tiles via LDS for the transpose; straight copy done during load.
// ---------------------------------------------------------------------------
__global__ __launch_bounds__(256) void k_transpose(const float* __restrict__ x,
                                                   bf16* __restrict__ xT,
                                                   bf16* __restrict__ xb)
{
    __shared__ float T[64][68];
    const int b = blockIdx.z;
    const int l0 = blockIdx.x * 64, d0 = blockIdx.y * 64;
    const int tid = threadIdx.x;
    const float* xsrc = x + ((size_t)b * LL + l0) * DD + d0;
    bf16* xbdst = xb + ((size_t)b * LL + l0) * DD + d0;
    #pragma unroll
    for (int it = 0; it < 4; ++it) {
        const int c = tid + it * 256;
        const int lr = c >> 4, cc = (c & 15) * 4;
        const float4 v = *(const float4*)(xsrc + (size_t)lr * DD + cc);
        T[lr][cc] = v.x; T[lr][cc + 1] = v.y; T[lr][cc + 2] = v.z; T[lr][cc + 3] = v.w;
        bf16x4 p = {(bf16)v.x, (bf16)v.y, (bf16)v.z, (bf16)v.w};
        *(bf16x4*)(xbdst + (size_t)lr * DD + cc) = p;
    }
    __syncthreads();
    const int dl = tid >> 2, ls = (tid & 3) * 16;
    bf16x8 p0, p1;
    #pragma unroll
    for (int j = 0; j < 8; ++j) p0[j] = (bf16)T[ls + j][dl];
    #pragma unroll
    for (int j = 0; j < 8; ++j) p1[j] = (bf16)T[ls + 8 + j][dl];
    bf16* o = xT + ((size_t)b * DD + d0 + dl) * LL + l0 + ls;
    *(bf16x8*)o = p0;
    *(bf16x8*)(o + 8) = p1;
}

// ---------------------------------------------------------------------------
// K1: wb[m, a] = bf16(tanh(sum_d xb[m,d] * W1b[a,d]))   M=B*L, N=DA, K=D
// ---------------------------------------------------------------------------
__global__ __launch_bounds__(256) void k_gemm1(const bf16* __restrict__ xb,
                                               const bf16* __restrict__ W1b,
                                               bf16* __restrict__ wb)
{
    const int n0 = blockIdx.x * 128;
    const size_t m0 = (size_t)blockIdx.y * 128;
    floatx4 acc[4][4];
    #pragma unroll
    for (int i = 0; i < 4; ++i)
        #pragma unroll
        for (int j = 0; j < 4; ++j) { floatx4 z = {0.f, 0.f, 0.f, 0.f}; acc[i][j] = z; }
    gemm_core(xb + m0 * DD, W1b + (size_t)n0 * DD, DD, DD, DD, acc);

    const int tid = threadIdx.x, lane = tid & 63, wv = tid >> 6;
    const int wr = wv >> 1, wc = wv & 1, lm = lane & 15, quad = lane >> 4;
    const size_t row0 = m0 + wr * 64 + quad * 4;
    const int col0 = n0 + wc * 64 + lm;
    #pragma unroll
    for (int i = 0; i < 4; ++i)
        #pragma unroll
        for (int j = 0; j < 4; ++j)
            #pragma unroll
            for (int r = 0; r < 4; ++r)
                wb[(row0 + i * 16 + r) * DA_ + col0 + j * 16] = (bf16)fast_tanh(acc[i][j][r]);
}

// ---------------------------------------------------------------------------
// K2: logitsb[b, n, l] = bf16(sum_a W2b[n,a] * wb[b*L+l, a])
// ---------------------------------------------------------------------------
__global__ __launch_bounds__(256) void k_gemm2(const bf16* __restrict__ wb,
                                               const bf16* __restrict__ W2b,
                                               bf16* __restrict__ logitsb)
{
    const int c0 = blockIdx.x * 128;   // global l index (never straddles a batch)
    const int m0 = blockIdx.y * 128;   // over NL
    floatx4 acc[4][4];
    #pragma unroll
    for (int i = 0; i < 4; ++i)
        #pragma unroll
        for (int j = 0; j < 4; ++j) { floatx4 z = {0.f, 0.f, 0.f, 0.f}; acc[i][j] = z; }
    gemm_core(W2b + (size_t)m0 * DA_, wb + (size_t)c0 * DA_, DA_, DA_, DA_, acc);

    const int b = c0 >> 11, lloc = c0 & (LL - 1);
    const int tid = threadIdx.x, lane = tid & 63, wv = tid >> 6;
    const int wr = wv >> 1, wc = wv & 1, lm = lane & 15, quad = lane >> 4;
    bf16* base = logitsb + ((size_t)b * NL_ + m0 + wr * 64 + quad * 4) * LL
               + lloc + wc * 64 + lm;
    #pragma unroll
    for (int i = 0; i < 4; ++i)
        #pragma unroll
        for (int j = 0; j < 4; ++j)
            #pragma unroll
            for (int r = 0; r < 4; ++r)
                base[(size_t)(i * 16 + r) * LL + j * 16] = (bf16)acc[i][j][r];
}

// ---------------------------------------------------------------------------
// K3: softmax over contiguous L per (b,n): read bf16 logits,
//     write fp32 att (output) + bf16 attb (for gemm3)
// ---------------------------------------------------------------------------
__global__ __launch_bounds__(256) void k_softmax(const bf16* __restrict__ logitsb,
                                                 float* __restrict__ att,
                                                 bf16* __restrict__ attb)
{
    const int tid = threadIdx.x;
    const bf16* p = logitsb + (size_t)blockIdx.x * LL;
    float* po = att + (size_t)blockIdx.x * LL;
    bf16* pb = attb + (size_t)blockIdx.x * LL;

    const bf16x8 v = *(const bf16x8*)(p + tid * 8);
    float f[8];
    #pragma unroll
    for (int j = 0; j < 8; ++j) f[j] = (float)v[j];

    __shared__ float red[8];
    float m = f[0];
    #pragma unroll
    for (int j = 1; j < 8; ++j) m = fmaxf(m, f[j]);
    #pragma unroll
    for (int off = 32; off; off >>= 1) m = fmaxf(m, __shfl_down(m, off));
    if ((tid & 63) == 0) red[tid >> 6] = m;
    __syncthreads();
    m = fmaxf(fmaxf(red[0], red[1]), fmaxf(red[2], red[3]));

    float s = 0.f;
    #pragma unroll
    for (int j = 0; j < 8; ++j) { f[j] = __expf(f[j] - m); s += f[j]; }
    #pragma unroll
    for (int off = 32; off; off >>= 1) s += __shfl_down(s, off);
    if ((tid & 63) == 0) red[4 + (tid >> 6)] = s;
    __syncthreads();
    s = red[4] + red[5] + red[6] + red[7];

    const float inv = 1.0f / s;
    float4 o0, o1;
    o0.x = f[0] * inv; o0.y = f[1] * inv; o0.z = f[2] * inv; o0.w = f[3] * inv;
    o1.x = f[4] * inv; o1.y = f[5] * inv; o1.z = f[6] * inv; o1.w = f[7] * inv;
    *(float4*)(po + tid * 8) = o0;
    *(float4*)(po + tid * 8 + 4) = o1;
    bf16x8 q = {(bf16)o0.x, (bf16)o0.y, (bf16)o0.z, (bf16)o0.w,
                (bf16)o1.x, (bf16)o1.y, (bf16)o1.z, (bf16)o1.w};
    *(bf16x8*)(pb + tid * 8) = q;
}

// ---------------------------------------------------------------------------
// K4: ctx[b, n, d] = sum_l attb[b,n,l] * xT[b,d,l]
// ---------------------------------------------------------------------------
__global__ __launch_bounds__(256) void k_gemm3(const bf16* __restrict__ attb,
                                               const bf16* __restrict__ xT,
                                               float* __restrict__ ctx)
{
    const int b = blockIdx.z;
    const int n0 = blockIdx.x * 128;   // over D
    const int m0 = blockIdx.y * 128;   // over NL
    floatx4 acc[4][4];
    #pragma unroll
    for (int i = 0; i < 4; ++i)
        #pragma unroll
        for (int j = 0; j < 4; ++j) { floatx4 z = {0.f, 0.f, 0.f, 0.f}; acc[i][j] = z; }
    gemm_core(attb + ((size_t)b * NL_ + m0) * LL,
              xT + ((size_t)b * DD + n0) * LL, LL, LL, LL, acc);

    const int tid = threadIdx.x, lane = tid & 63, wv = tid >> 6;
    const int wr = wv >> 1, wc = wv & 1, lm = lane & 15, quad = lane >> 4;
    float* base = ctx + ((size_t)b * NL_ + m0 + wr * 64 + quad * 4) * DD
                + n0 + wc * 64 + lm;
    #pragma unroll
    for (int i = 0; i < 4; ++i)
        #pragma unroll
        for (int j = 0; j < 4; ++j)
            #pragma unroll
            for (int r = 0; r < 4; ++r)
                base[(size_t)(i * 16 + r) * DD + j * 16] = acc[i][j][r];
}

// ---------------------------------------------------------------------------
// K5: wo[b, n] = sum_d ctx[b,n,d] * W3[n,d] + b3[n]   (one wave per (b,n))
// ---------------------------------------------------------------------------
__global__ __launch_bounds__(256) void k_wo(
    const float* __restrict__ ctx, const float* __restrict__ W3,
    const float* __restrict__ b3, float* __restrict__ wo)
{
    const int gw = blockIdx.x * 4 + (threadIdx.x >> 6);
    const int lane = threadIdx.x & 63;
    const int n = gw & (NL_ - 1);
    const float* c = ctx + (size_t)gw * DD;
    const float* w = W3 + (size_t)n * DD;
    float s = 0.f;
    #pragma unroll
    for (int it = 0; it < 2; ++it) {
        const float4 a = *(const float4*)&c[(it * 64 + lane) * 4];
        const float4 b = *(const float4*)&w[(it * 64 + lane) * 4];
        s += a.x * b.x + a.y * b.y + a.z * b.z + a.w * b.w;
    }
    #pragma unroll
    for (int off = 32; off; off >>= 1) s += __shfl_down(s, off);
    if (lane == 0) wo[gw] = s + b3[n];
}

// ---------------------------------------------------------------------------
extern "C" void kernel_launch(void* const* d_in, const int* in_sizes, int n_in,
                              void* d_out, int out_size, void* d_ws, size_t ws_size,
                              hipStream_t stream)
{
    const float* x  = (const float*)d_in[0];
    const float* W1 = (const float*)d_in[1];
    const float* W2 = (const float*)d_in[2];
    const float* W3 = (const float*)d_in[3];
    const float* b3 = (const float*)d_in[4];

    float* out = (float*)d_out;
    float* ctx = out;                               // [B, NL, D]
    float* wo  = out + (size_t)BB * NL_ * DD;       // [B, NL]
    float* att = wo + (size_t)BB * NL_;             // [B, NL, L]

    // ws layout (193 MB; proven ws >= ~500 MB from harness poison size):
    //   R0 xT [B,D,L]          64 MB
    //   R1 xb [B*L,D] -> logitsb [B,NL,L]  64 MB (xb dead after gemm1)
    //   R2 wb [B*L,DA] -> attb [B,NL,L]    64 MB (wb dead after gemm2)
    //   R3 W1b, W2b            1 MB
    char* wsp = (char*)d_ws;
    const size_t M64 = (size_t)64 * 1024 * 1024;
    bf16* xT      = (bf16*)(wsp);
    bf16* xb      = (bf16*)(wsp + M64);
    bf16* logitsb = (bf16*)(wsp + M64);
    bf16* wb      = (bf16*)(wsp + 2 * M64);
    bf16* attb    = (bf16*)(wsp + 2 * M64);
    bf16* W1b     = (bf16*)(wsp + 3 * M64);
    bf16* W2b     = W1b + (size_t)DA_ * DD;

    k_cvt<<<(DA_ * DD) / 1024, 256, 0, stream>>>(W1, W1b, DA_ * DD);
    k_cvt<<<(NL_ * DA_) / 1024, 256, 0, stream>>>(W2, W2b, NL_ * DA_);
    k_transpose<<<dim3(LL / 64, DD / 64, BB), 256, 0, stream>>>(x, xT, xb);
    k_gemm1<<<dim3(DA_ / 128, (BB * LL) / 128), 256, 0, stream>>>(xb, W1b, wb);
    k_gemm2<<<dim3((BB * LL) / 128, NL_ / 128), 256, 0, stream>>>(wb, W2b, logitsb);
    k_softmax<<<BB * NL_, 256, 0, stream>>>(logitsb, att, attb);
    k_gemm3<<<dim3(DD / 128, NL_ / 128, BB), 256, 0, stream>>>(attb, xT, ctx);
    k_wo<<<(BB * NL_) / 4, 256, 0, stream>>>(ctx, W3, b3, wo);
}